// Round 1
// baseline (1160.192 us; speedup 1.0000x reference)
//
#include <hip/hip_runtime.h>

typedef _Float16 f16x8 __attribute__((ext_vector_type(8)));
typedef _Float16 f16x4 __attribute__((ext_vector_type(4)));
typedef float    f32x4 __attribute__((ext_vector_type(4)));

#define BM 128
#define BN 128
#define BK 32

// ---------------------------------------------------------------- helpers

__device__ __forceinline__ void async16(void* lds, const void* g) {
    __builtin_amdgcn_global_load_lds(
        (const __attribute__((address_space(1))) unsigned int*)g,
        (__attribute__((address_space(3))) unsigned int*)lds, 16, 0, 0);
}

// one MFMA K-step (K=32) for a 4-wave 128x128 tile; wave (wr,wc) owns 64x64
__device__ __forceinline__ void mfma_step(const _Float16* As, const _Float16* Bs,
                                          f32x4 (&acc)[4][4], int lane, int wr, int wc) {
    const int kk = (lane >> 4) * 8;
    const int rr = lane & 15;
    f16x8 af[4], bf[4];
#pragma unroll
    for (int mi = 0; mi < 4; mi++)
        af[mi] = *(const f16x8*)(As + (size_t)(wr * 64 + mi * 16 + rr) * BK + kk);
#pragma unroll
    for (int ni = 0; ni < 4; ni++)
        bf[ni] = *(const f16x8*)(Bs + (size_t)(wc * 64 + ni * 16 + rr) * BK + kk);
#pragma unroll
    for (int mi = 0; mi < 4; mi++)
#pragma unroll
        for (int ni = 0; ni < 4; ni++)
            acc[mi][ni] = __builtin_amdgcn_mfma_f32_16x16x32_f16(af[mi], bf[ni], acc[mi][ni], 0, 0, 0);
}

// fused BN-affine epilogue: z = y*alpha[n] + beta[n]
__device__ __forceinline__ void epilogue(f32x4 (&acc)[4][4], float* __restrict__ C,
                                         const float* __restrict__ bias,
                                         const float* __restrict__ mean,
                                         const float* __restrict__ var,
                                         const float* __restrict__ bnw,
                                         const float* __restrict__ bnb,
                                         float s, int m0, int n0, int N,
                                         int lane, int wr, int wc) {
    const int colbase = n0 + wc * 64 + (lane & 15);
    const int rowbase = m0 + wr * 64 + ((lane >> 4) << 2);
#pragma unroll
    for (int ni = 0; ni < 4; ni++) {
        const int col = colbase + ni * 16;
        const float r     = rsqrtf(var[col] + 1e-5f);
        const float alpha = r * bnw[col] * s;
        const float beta  = (bias[col] - mean[col]) * alpha + bnb[col] * s;
#pragma unroll
        for (int mi = 0; mi < 4; mi++)
#pragma unroll
            for (int i = 0; i < 4; i++)
                C[(size_t)(rowbase + mi * 16 + i) * N + col] = acc[mi][ni][i] * alpha + beta;
    }
}

// ---------------------------------------------------------------- converts

__global__ __launch_bounds__(256) void cvt_x_kernel(const float4* __restrict__ in,
                                                    f16x4* __restrict__ outp, long n4) {
    long i = (long)blockIdx.x * blockDim.x + threadIdx.x;
    const long stride = (long)gridDim.x * blockDim.x;
    for (; i < n4; i += stride) {
        float4 v = in[i];
        f16x4 h = { (_Float16)v.x, (_Float16)v.y, (_Float16)v.z, (_Float16)v.w };
        outp[i] = h;
    }
}

// w [K][N] fp32 -> wt [N][K] fp16
__global__ __launch_bounds__(256) void transpose_w_kernel(const float* __restrict__ w,
                                                          _Float16* __restrict__ wt,
                                                          int K, int N) {
    __shared__ _Float16 tile[32][33];
    const int n0 = blockIdx.x * 32;
    const int k0 = blockIdx.y * 32;
    for (int i = threadIdx.y; i < 32; i += 8)
        tile[i][threadIdx.x] = (_Float16)w[(size_t)(k0 + i) * N + n0 + threadIdx.x];
    __syncthreads();
    for (int i = threadIdx.y; i < 32; i += 8)
        wt[(size_t)(n0 + i) * K + k0 + threadIdx.x] = tile[threadIdx.x][i];
}

// ---------------------------------------------------------------- fast GEMM
// A [M][K] fp16 (k-contig), BT [N][K] fp16 (k-contig), C [M][N] fp32 = z

__global__ __launch_bounds__(256) void gemm_f16_bn(const _Float16* __restrict__ A,
                                                   const _Float16* __restrict__ BT,
                                                   float* __restrict__ C,
                                                   const float* __restrict__ bias,
                                                   const float* __restrict__ mean,
                                                   const float* __restrict__ var,
                                                   const float* __restrict__ bnw,
                                                   const float* __restrict__ bnb,
                                                   const float* __restrict__ scalep,
                                                   int M, int N, int K) {
    __shared__ _Float16 As[BM * BK];
    __shared__ _Float16 Bs[BN * BK];

    // bijective XCD swizzle (grid divisible by 8 here)
    const int nwg = gridDim.x;
    const int cpx = nwg >> 3;
    int bid = blockIdx.x;
    int swz = ((nwg & 7) == 0) ? (bid & 7) * cpx + (bid >> 3) : bid;
    const int ntn = N / BN;
    const int tm = swz / ntn, tn = swz % ntn;
    const int m0 = tm * BM, n0 = tn * BN;

    const int t = threadIdx.x;
    const int lane = t & 63, w = t >> 6;
    const int wr = w >> 1, wc = w & 1;

    // staging chunks: 512 x 16B per operand tile, lane-linear per wave
    const int c0 = t, c1 = t + 256;
    const _Float16* gA0 = A + (size_t)(m0 + (c0 >> 2)) * K + (c0 & 3) * 8;
    const _Float16* gA1 = A + (size_t)(m0 + (c1 >> 2)) * K + (c1 & 3) * 8;
    const _Float16* gB0 = BT + (size_t)(n0 + (c0 >> 2)) * K + (c0 & 3) * 8;
    const _Float16* gB1 = BT + (size_t)(n0 + (c1 >> 2)) * K + (c1 & 3) * 8;
    _Float16* lA0 = &As[c0 * 8]; _Float16* lA1 = &As[c1 * 8];
    _Float16* lB0 = &Bs[c0 * 8]; _Float16* lB1 = &Bs[c1 * 8];

    f32x4 acc[4][4] = {};

    for (int k0 = 0; k0 < K; k0 += BK) {
        async16(lA0, gA0 + k0);
        async16(lA1, gA1 + k0);
        async16(lB0, gB0 + k0);
        async16(lB1, gB1 + k0);
        __syncthreads();
        mfma_step(As, Bs, acc, lane, wr, wc);
        __syncthreads();
    }

    epilogue(acc, C, bias, mean, var, bnw, bnb, scalep[0], m0, n0, N, lane, wr, wc);
}

// ------------------------------------------------- fallback GEMM (no ws):
// reads fp32 x and w directly, converts + transposes B during LDS staging

__global__ __launch_bounds__(256) void gemm_f32src_bn(const float* __restrict__ X,
                                                      const float* __restrict__ W,
                                                      float* __restrict__ C,
                                                      const float* __restrict__ bias,
                                                      const float* __restrict__ mean,
                                                      const float* __restrict__ var,
                                                      const float* __restrict__ bnw,
                                                      const float* __restrict__ bnb,
                                                      const float* __restrict__ scalep,
                                                      int M, int N, int K) {
    __shared__ _Float16 As[BM * BK];
    __shared__ _Float16 Bs[BN * BK];

    const int nwg = gridDim.x;
    const int cpx = nwg >> 3;
    int bid = blockIdx.x;
    int swz = ((nwg & 7) == 0) ? (bid & 7) * cpx + (bid >> 3) : bid;
    const int ntn = N / BN;
    const int tm = swz / ntn, tn = swz % ntn;
    const int m0 = tm * BM, n0 = tn * BN;

    const int t = threadIdx.x;
    const int lane = t & 63, w = t >> 6;
    const int wr = w >> 1, wc = w & 1;

    f32x4 acc[4][4] = {};

    for (int k0 = 0; k0 < K; k0 += BK) {
        __syncthreads();
        // A tile: 128 rows x 32 cols fp32 -> fp16
#pragma unroll
        for (int p = 0; p < 4; p++) {
            const int r = p * 32 + (t >> 3);
            const int c = (t & 7) * 4;
            float4 v = *(const float4*)&X[(size_t)(m0 + r) * K + k0 + c];
            f16x4 h = { (_Float16)v.x, (_Float16)v.y, (_Float16)v.z, (_Float16)v.w };
            *(f16x4*)&As[(size_t)r * BK + c] = h;
        }
        // B tile: 32 k-rows x 128 n-cols fp32, scatter-transposed to [n][k] fp16
#pragma unroll
        for (int p = 0; p < 4; p++) {
            const int kk = p * 8 + (t >> 5);
            const int nn = (t & 31) * 4;
            float4 v = *(const float4*)&W[(size_t)(k0 + kk) * N + n0 + nn];
            Bs[(size_t)(nn + 0) * BK + kk] = (_Float16)v.x;
            Bs[(size_t)(nn + 1) * BK + kk] = (_Float16)v.y;
            Bs[(size_t)(nn + 2) * BK + kk] = (_Float16)v.z;
            Bs[(size_t)(nn + 3) * BK + kk] = (_Float16)v.w;
        }
        __syncthreads();
        mfma_step(As, Bs, acc, lane, wr, wc);
    }

    epilogue(acc, C, bias, mean, var, bnw, bnb, scalep[0], m0, n0, N, lane, wr, wc);
}

// ---------------------------------------------------------------- softmax
// one block per row, N == 4096, in-place on fp32

__global__ __launch_bounds__(256) void softmax_rows(float* __restrict__ out, int N) {
    __shared__ float red[8];
    float4* p = (float4*)(out + (size_t)blockIdx.x * N);
    const int t = threadIdx.x;
    const int lane = t & 63, wid = t >> 6;

    float4 v[4];
    float mx = -3.4e38f;
#pragma unroll
    for (int i = 0; i < 4; i++) {
        v[i] = p[t + 256 * i];
        mx = fmaxf(mx, fmaxf(fmaxf(v[i].x, v[i].y), fmaxf(v[i].z, v[i].w)));
    }
#pragma unroll
    for (int off = 32; off >= 1; off >>= 1) mx = fmaxf(mx, __shfl_xor(mx, off));
    if (lane == 0) red[wid] = mx;
    __syncthreads();
    mx = fmaxf(fmaxf(red[0], red[1]), fmaxf(red[2], red[3]));

    float sum = 0.f;
#pragma unroll
    for (int i = 0; i < 4; i++) {
        v[i].x = __expf(v[i].x - mx); v[i].y = __expf(v[i].y - mx);
        v[i].z = __expf(v[i].z - mx); v[i].w = __expf(v[i].w - mx);
        sum += v[i].x + v[i].y + v[i].z + v[i].w;
    }
#pragma unroll
    for (int off = 32; off >= 1; off >>= 1) sum += __shfl_xor(sum, off);
    if (lane == 0) red[4 + wid] = sum;
    __syncthreads();
    sum = red[4] + red[5] + red[6] + red[7];

    const float inv = 1.0f / sum;
#pragma unroll
    for (int i = 0; i < 4; i++) {
        v[i].x *= inv; v[i].y *= inv; v[i].z *= inv; v[i].w *= inv;
        p[t + 256 * i] = v[i];
    }
}

// ---------------------------------------------------------------- launch

extern "C" void kernel_launch(void* const* d_in, const int* in_sizes, int n_in,
                              void* d_out, int out_size, void* d_ws, size_t ws_size,
                              hipStream_t stream) {
    const float* x     = (const float*)d_in[0];
    const float* w     = (const float*)d_in[1];
    const float* bias  = (const float*)d_in[2];
    const float* mean  = (const float*)d_in[3];
    const float* var   = (const float*)d_in[4];
    const float* bnw   = (const float*)d_in[5];
    const float* bnb   = (const float*)d_in[6];
    const float* scale = (const float*)d_in[7];
    float* out = (float*)d_out;

    const int N = in_sizes[2];
    const int K = in_sizes[1] / N;
    const int M = in_sizes[0] / K;

    const size_t xh_bytes = (size_t)M * K * sizeof(_Float16);
    const size_t wh_bytes = (size_t)N * K * sizeof(_Float16);
    const int nblocks = (M / BM) * (N / BN);

    if (ws_size >= xh_bytes + wh_bytes) {
        _Float16* x16 = (_Float16*)d_ws;
        _Float16* wt16 = (_Float16*)((char*)d_ws + xh_bytes);
        cvt_x_kernel<<<2048, 256, 0, stream>>>((const float4*)x, (f16x4*)x16,
                                               (long)M * K / 4);
        transpose_w_kernel<<<dim3(N / 32, K / 32), dim3(32, 8), 0, stream>>>(w, wt16, K, N);
        gemm_f16_bn<<<nblocks, 256, 0, stream>>>(x16, wt16, out, bias, mean, var,
                                                 bnw, bnb, scale, M, N, K);
    } else {
        gemm_f32src_bn<<<nblocks, 256, 0, stream>>>(x, w, out, bias, mean, var,
                                                    bnw, bnb, scale, M, N, K);
    }
    softmax_rows<<<M, 256, 0, stream>>>(out, N);
}

// Round 2
// 1037.930 us; speedup vs baseline: 1.1178x; 1.1178x over previous
//
#include <hip/hip_runtime.h>

typedef _Float16 f16x8 __attribute__((ext_vector_type(8)));
typedef _Float16 f16x4 __attribute__((ext_vector_type(4)));
typedef float    f32x4 __attribute__((ext_vector_type(4)));

#define BM 128
#define BN 128
#define BK 32

// ---------------------------------------------------------------- helpers

__device__ __forceinline__ void async16(void* lds, const void* g) {
    __builtin_amdgcn_global_load_lds(
        (const __attribute__((address_space(1))) unsigned int*)g,
        (__attribute__((address_space(3))) unsigned int*)lds, 16, 0, 0);
}

// one MFMA K-step (K=32) for a 4-wave 128x128 tile; wave (wr,wc) owns 64x64
__device__ __forceinline__ void mfma_step(const _Float16* As, const _Float16* Bs,
                                          f32x4 (&acc)[4][4], int lane, int wr, int wc) {
    const int kk = (lane >> 4) * 8;
    const int rr = lane & 15;
    f16x8 af[4], bf[4];
#pragma unroll
    for (int mi = 0; mi < 4; mi++)
        af[mi] = *(const f16x8*)(As + (size_t)(wr * 64 + mi * 16 + rr) * BK + kk);
#pragma unroll
    for (int ni = 0; ni < 4; ni++)
        bf[ni] = *(const f16x8*)(Bs + (size_t)(wc * 64 + ni * 16 + rr) * BK + kk);
#pragma unroll
    for (int mi = 0; mi < 4; mi++)
#pragma unroll
        for (int ni = 0; ni < 4; ni++)
            acc[mi][ni] = __builtin_amdgcn_mfma_f32_16x16x32_f16(af[mi], bf[ni], acc[mi][ni], 0, 0, 0);
}

// fused BN-affine epilogue: z = y*alpha[n] + beta[n]; nontemporal stores so the
// 256MB fp32 C-stream does not evict A/B panels from L2/L3 during the GEMM.
__device__ __forceinline__ void epilogue(f32x4 (&acc)[4][4], float* __restrict__ C,
                                         const float* __restrict__ bias,
                                         const float* __restrict__ mean,
                                         const float* __restrict__ var,
                                         const float* __restrict__ bnw,
                                         const float* __restrict__ bnb,
                                         float s, int m0, int n0, int N,
                                         int lane, int wr, int wc) {
    const int colbase = n0 + wc * 64 + (lane & 15);
    const int rowbase = m0 + wr * 64 + ((lane >> 4) << 2);
#pragma unroll
    for (int ni = 0; ni < 4; ni++) {
        const int col = colbase + ni * 16;
        const float r     = rsqrtf(var[col] + 1e-5f);
        const float alpha = r * bnw[col] * s;
        const float beta  = (bias[col] - mean[col]) * alpha + bnb[col] * s;
#pragma unroll
        for (int mi = 0; mi < 4; mi++)
#pragma unroll
            for (int i = 0; i < 4; i++)
                __builtin_nontemporal_store(acc[mi][ni][i] * alpha + beta,
                    &C[(size_t)(rowbase + mi * 16 + i) * N + col]);
    }
}

// ---------------------------------------------------------------- converts

__global__ __launch_bounds__(256) void cvt_x_kernel(const float4* __restrict__ in,
                                                    f16x4* __restrict__ outp, long n4) {
    long i = (long)blockIdx.x * blockDim.x + threadIdx.x;
    const long stride = (long)gridDim.x * blockDim.x;
    for (; i < n4; i += stride) {
        float4 v = in[i];
        f16x4 h = { (_Float16)v.x, (_Float16)v.y, (_Float16)v.z, (_Float16)v.w };
        outp[i] = h;
    }
}

// w [K][N] fp32 -> wt [N][K] fp16
__global__ __launch_bounds__(256) void transpose_w_kernel(const float* __restrict__ w,
                                                          _Float16* __restrict__ wt,
                                                          int K, int N) {
    __shared__ _Float16 tile[32][33];
    const int n0 = blockIdx.x * 32;
    const int k0 = blockIdx.y * 32;
    for (int i = threadIdx.y; i < 32; i += 8)
        tile[i][threadIdx.x] = (_Float16)w[(size_t)(k0 + i) * N + n0 + threadIdx.x];
    __syncthreads();
    for (int i = threadIdx.y; i < 32; i += 8)
        wt[(size_t)(n0 + i) * K + k0 + threadIdx.x] = tile[threadIdx.x][i];
}

// ---------------------------------------------------------------- fast GEMM
// A [M][K] fp16 (k-contig), BT [N][K] fp16 (k-contig), C [M][N] fp32 = z
// Double-buffered LDS, issue-early prefetch (T3 minimum recipe):
//   STAGE(next) -> compute(cur) -> __syncthreads (vmcnt0+lgkmcnt0+barrier)

__global__ __launch_bounds__(256) void gemm_f16_bn(const _Float16* __restrict__ A,
                                                   const _Float16* __restrict__ BT,
                                                   float* __restrict__ C,
                                                   const float* __restrict__ bias,
                                                   const float* __restrict__ mean,
                                                   const float* __restrict__ var,
                                                   const float* __restrict__ bnw,
                                                   const float* __restrict__ bnb,
                                                   const float* __restrict__ scalep,
                                                   int M, int N, int K) {
    __shared__ _Float16 As[2][BM * BK];
    __shared__ _Float16 Bs[2][BN * BK];

    // bijective XCD swizzle (grid divisible by 8 here)
    const int nwg = gridDim.x;
    const int cpx = nwg >> 3;
    int bid = blockIdx.x;
    int swz = ((nwg & 7) == 0) ? (bid & 7) * cpx + (bid >> 3) : bid;
    const int ntn = N / BN;
    const int tm = swz / ntn, tn = swz % ntn;
    const int m0 = tm * BM, n0 = tn * BN;

    const int t = threadIdx.x;
    const int lane = t & 63, w = t >> 6;
    const int wr = w >> 1, wc = w & 1;

    // staging chunks: 512 x 16B per operand tile, lane-linear per wave
    const int c0 = t, c1 = t + 256;
    const int o0 = c0 * 8, o1 = c1 * 8;   // halfs; *16B linear LDS dest
    const _Float16* gA0 = A + (size_t)(m0 + (c0 >> 2)) * K + (c0 & 3) * 8;
    const _Float16* gA1 = A + (size_t)(m0 + (c1 >> 2)) * K + (c1 & 3) * 8;
    const _Float16* gB0 = BT + (size_t)(n0 + (c0 >> 2)) * K + (c0 & 3) * 8;
    const _Float16* gB1 = BT + (size_t)(n0 + (c1 >> 2)) * K + (c1 & 3) * 8;

    f32x4 acc[4][4] = {};

    // prologue: stage tile 0 into buf 0
    async16(&As[0][o0], gA0);
    async16(&As[0][o1], gA1);
    async16(&Bs[0][o0], gB0);
    async16(&Bs[0][o1], gB1);
    __syncthreads();

    int cur = 0;
    for (int k0 = BK; k0 < K; k0 += BK) {
        const int nxt = cur ^ 1;
        // issue next-tile loads first: flight overlaps this tile's compute
        async16(&As[nxt][o0], gA0 + k0);
        async16(&As[nxt][o1], gA1 + k0);
        async16(&Bs[nxt][o0], gB0 + k0);
        async16(&Bs[nxt][o1], gB1 + k0);
        mfma_step(As[cur], Bs[cur], acc, lane, wr, wc);
        __syncthreads();   // drains vmcnt(0)+lgkmcnt(0): next tile ready, WAR safe
        cur = nxt;
    }
    mfma_step(As[cur], Bs[cur], acc, lane, wr, wc);   // last tile, no prefetch

    epilogue(acc, C, bias, mean, var, bnw, bnb, scalep[0], m0, n0, N, lane, wr, wc);
}

// ------------------------------------------------- fallback GEMM (no ws):
// reads fp32 x and w directly, converts + transposes B during LDS staging

__global__ __launch_bounds__(256) void gemm_f32src_bn(const float* __restrict__ X,
                                                      const float* __restrict__ W,
                                                      float* __restrict__ C,
                                                      const float* __restrict__ bias,
                                                      const float* __restrict__ mean,
                                                      const float* __restrict__ var,
                                                      const float* __restrict__ bnw,
                                                      const float* __restrict__ bnb,
                                                      const float* __restrict__ scalep,
                                                      int M, int N, int K) {
    __shared__ _Float16 As[BM * BK];
    __shared__ _Float16 Bs[BN * BK];

    const int nwg = gridDim.x;
    const int cpx = nwg >> 3;
    int bid = blockIdx.x;
    int swz = ((nwg & 7) == 0) ? (bid & 7) * cpx + (bid >> 3) : bid;
    const int ntn = N / BN;
    const int tm = swz / ntn, tn = swz % ntn;
    const int m0 = tm * BM, n0 = tn * BN;

    const int t = threadIdx.x;
    const int lane = t & 63, w = t >> 6;
    const int wr = w >> 1, wc = w & 1;

    f32x4 acc[4][4] = {};

    for (int k0 = 0; k0 < K; k0 += BK) {
        __syncthreads();
#pragma unroll
        for (int p = 0; p < 4; p++) {
            const int r = p * 32 + (t >> 3);
            const int c = (t & 7) * 4;
            float4 v = *(const float4*)&X[(size_t)(m0 + r) * K + k0 + c];
            f16x4 h = { (_Float16)v.x, (_Float16)v.y, (_Float16)v.z, (_Float16)v.w };
            *(f16x4*)&As[(size_t)r * BK + c] = h;
        }
#pragma unroll
        for (int p = 0; p < 4; p++) {
            const int kk = p * 8 + (t >> 5);
            const int nn = (t & 31) * 4;
            float4 v = *(const float4*)&W[(size_t)(k0 + kk) * N + n0 + nn];
            Bs[(size_t)(nn + 0) * BK + kk] = (_Float16)v.x;
            Bs[(size_t)(nn + 1) * BK + kk] = (_Float16)v.y;
            Bs[(size_t)(nn + 2) * BK + kk] = (_Float16)v.z;
            Bs[(size_t)(nn + 3) * BK + kk] = (_Float16)v.w;
        }
        __syncthreads();
        mfma_step(As, Bs, acc, lane, wr, wc);
    }

    epilogue(acc, C, bias, mean, var, bnw, bnb, scalep[0], m0, n0, N, lane, wr, wc);
}

// ---------------------------------------------------------------- softmax
// one block per row, N == 4096, in-place on fp32

__global__ __launch_bounds__(256) void softmax_rows(float* __restrict__ out, int N) {
    __shared__ float red[8];
    float4* p = (float4*)(out + (size_t)blockIdx.x * N);
    const int t = threadIdx.x;
    const int lane = t & 63, wid = t >> 6;

    float4 v[4];
    float mx = -3.4e38f;
#pragma unroll
    for (int i = 0; i < 4; i++) {
        v[i] = p[t + 256 * i];
        mx = fmaxf(mx, fmaxf(fmaxf(v[i].x, v[i].y), fmaxf(v[i].z, v[i].w)));
    }
#pragma unroll
    for (int off = 32; off >= 1; off >>= 1) mx = fmaxf(mx, __shfl_xor(mx, off));
    if (lane == 0) red[wid] = mx;
    __syncthreads();
    mx = fmaxf(fmaxf(red[0], red[1]), fmaxf(red[2], red[3]));

    float sum = 0.f;
#pragma unroll
    for (int i = 0; i < 4; i++) {
        v[i].x = __expf(v[i].x - mx); v[i].y = __expf(v[i].y - mx);
        v[i].z = __expf(v[i].z - mx); v[i].w = __expf(v[i].w - mx);
        sum += v[i].x + v[i].y + v[i].z + v[i].w;
    }
#pragma unroll
    for (int off = 32; off >= 1; off >>= 1) sum += __shfl_xor(sum, off);
    if (lane == 0) red[4 + wid] = sum;
    __syncthreads();
    sum = red[4] + red[5] + red[6] + red[7];

    const float inv = 1.0f / sum;
#pragma unroll
    for (int i = 0; i < 4; i++) {
        v[i].x *= inv; v[i].y *= inv; v[i].z *= inv; v[i].w *= inv;
        p[t + 256 * i] = v[i];
    }
}

// ---------------------------------------------------------------- launch

extern "C" void kernel_launch(void* const* d_in, const int* in_sizes, int n_in,
                              void* d_out, int out_size, void* d_ws, size_t ws_size,
                              hipStream_t stream) {
    const float* x     = (const float*)d_in[0];
    const float* w     = (const float*)d_in[1];
    const float* bias  = (const float*)d_in[2];
    const float* mean  = (const float*)d_in[3];
    const float* var   = (const float*)d_in[4];
    const float* bnw   = (const float*)d_in[5];
    const float* bnb   = (const float*)d_in[6];
    const float* scale = (const float*)d_in[7];
    float* out = (float*)d_out;

    const int N = in_sizes[2];
    const int K = in_sizes[1] / N;
    const int M = in_sizes[0] / K;

    const size_t xh_bytes = (size_t)M * K * sizeof(_Float16);
    const size_t wh_bytes = (size_t)N * K * sizeof(_Float16);
    const int nblocks = (M / BM) * (N / BN);

    if (ws_size >= xh_bytes + wh_bytes) {
        _Float16* x16 = (_Float16*)d_ws;
        _Float16* wt16 = (_Float16*)((char*)d_ws + xh_bytes);
        cvt_x_kernel<<<2048, 256, 0, stream>>>((const float4*)x, (f16x4*)x16,
                                               (long)M * K / 4);
        transpose_w_kernel<<<dim3(N / 32, K / 32), dim3(32, 8), 0, stream>>>(w, wt16, K, N);
        gemm_f16_bn<<<nblocks, 256, 0, stream>>>(x16, wt16, out, bias, mean, var,
                                                 bnw, bnb, scale, M, N, K);
    } else {
        gemm_f32src_bn<<<nblocks, 256, 0, stream>>>(x, w, out, bias, mean, var,
                                                    bnw, bnb, scale, M, N, K);
    }
    softmax_rows<<<M, 256, 0, stream>>>(out, N);
}

// Round 4
// 773.384 us; speedup vs baseline: 1.5002x; 1.3421x over previous
//
#include <hip/hip_runtime.h>

typedef _Float16 f16x8 __attribute__((ext_vector_type(8)));
typedef _Float16 f16x4 __attribute__((ext_vector_type(4)));
typedef float    f32x4 __attribute__((ext_vector_type(4)));

// ---------------------------------------------------------------- helpers

__device__ __forceinline__ void async16(void* lds, const void* g) {
    __builtin_amdgcn_global_load_lds(
        (const __attribute__((address_space(1))) unsigned int*)g,
        (__attribute__((address_space(3))) unsigned int*)lds, 16, 0, 0);
}

#define MEMF() asm volatile("" ::: "memory")
__device__ __forceinline__ void BAR() { MEMF(); __builtin_amdgcn_s_barrier(); MEMF(); }
#define VMWAIT(N) asm volatile("s_waitcnt vmcnt(" #N ")" ::: "memory")

// swizzled LDS fragment read: tile row-major [256 rows][64B], byte col XORed by
// ((row>>1)&3)<<4  ->  16 rows of a frag-read spread over 8 bank-quads (2-way, free)
__device__ __forceinline__ f16x8 frag_ld(const _Float16* buf, int row, int kq) {
    const char* p = (const char*)buf + row * 64 + ((kq << 4) ^ (((row >> 1) & 3) << 4));
    return *(const f16x8*)p;
}

// ------------------------------------------------- 8-phase-style 256x256 GEMM
// A [M][K] fp16, BT [N][K] fp16, C = (A*BT^T)*alpha+beta  [M][N] fp32
// 8 waves (2Mx4N), BK=32, ring-4 LDS (128KiB), counted vmcnt(8) per K-tile.
//
// Ledger: tile t lives in slot t&3. During tile t we stage tile t+3 (A in
// phase 0, B in phase 1). Slot s=t&3 is re-written by tile t+4, whose loads
// issue after tile t's final barrier -- by which every wave's tile-t ds_reads
// completed (compiler lgkmcnt precedes the MFMAs that precede the barrier)
// => WAR safe. vmcnt(8) before the tile-end barrier guarantees each wave's
// share of tile t+1's loads landed (outstanding = t+2,t+3 = 8) => RAW safe.
// Tail: peel last 3 tiles with vmcnt(4)/vmcnt(0)/none.

__global__ __launch_bounds__(512, 2) void gemm_f16_bn_8p(
        const _Float16* __restrict__ A, const _Float16* __restrict__ BT,
        float* __restrict__ C,
        const float* __restrict__ bias, const float* __restrict__ mean,
        const float* __restrict__ var,  const float* __restrict__ bnw,
        const float* __restrict__ bnb,  const float* __restrict__ scalep,
        int M, int N, int K) {
    __shared__ __align__(16) _Float16 ldsA[4][8192];   // 4 x 256x32 fp16 = 64KB
    __shared__ __align__(16) _Float16 ldsB[4][8192];   // 64KB

    // bijective XCD swizzle (grid = 1024, divisible by 8)
    const int nwg = gridDim.x;
    const int cpx = nwg >> 3;
    int bid = blockIdx.x;
    int swz = ((nwg & 7) == 0) ? (bid & 7) * cpx + (bid >> 3) : bid;
    const int ntn = N >> 8;
    const int m0 = (swz / ntn) << 8, n0 = (swz % ntn) << 8;

    const int t = threadIdx.x;
    const int lane = t & 63, wid = t >> 6;
    const int wr = wid >> 2, wc = wid & 3;          // 2M x 4N waves
    const int rr = lane & 15, kq = lane >> 4;
    const int arow = wr * 128, brow = wc * 64;

    // staging: 1024 16B-chunks per operand tile; thread handles chunks t, t+512.
    // chunk c -> LDS bytes [c*16, c*16+16) (linear, = wave-base + lane*16);
    // source column pre-XORed so a swizzled read returns linear data.
    const int c0 = t, c1 = t + 512;
    const int r0 = c0 >> 2, r1 = c1 >> 2;
    const int sc0 = (((c0 & 3) << 4) ^ (((r0 >> 1) & 3) << 4)) >> 1;
    const int sc1 = (((c1 & 3) << 4) ^ (((r1 >> 1) & 3) << 4)) >> 1;
    const _Float16* gA0 = A  + (size_t)(m0 + r0) * K + sc0;
    const _Float16* gA1 = A  + (size_t)(m0 + r1) * K + sc1;
    const _Float16* gB0 = BT + (size_t)(n0 + r0) * K + sc0;
    const _Float16* gB1 = BT + (size_t)(n0 + r1) * K + sc1;
    char* const adst0 = (char*)&ldsA[0][0] + (size_t)c0 * 16;
    char* const adst1 = (char*)&ldsA[0][0] + (size_t)c1 * 16;
    char* const bdst0 = (char*)&ldsB[0][0] + (size_t)c0 * 16;
    char* const bdst1 = (char*)&ldsB[0][0] + (size_t)c1 * 16;

    f32x4 acc[8][4] = {};

    const int NT = K >> 5;   // 128

    // prologue: stage tiles 0,1,2
#pragma unroll
    for (int ts = 0; ts < 3; ++ts) {
        async16(adst0 + ts * 16384, gA0 + ts * 32);
        async16(adst1 + ts * 16384, gA1 + ts * 32);
        async16(bdst0 + ts * 16384, gB0 + ts * 32);
        async16(bdst1 + ts * 16384, gB1 + ts * 32);
    }
    VMWAIT(8);        // own tile-0 loads done (8 = tiles 1,2 in flight)
    BAR();            // => everyone's tile-0 loads done

#define TILE_STEP(SLOT, STAGE, KSRC, WAITSTMT)                                   \
  do {                                                                           \
    const _Float16* Ab = ldsA[SLOT];                                             \
    const _Float16* Bb = ldsB[SLOT];                                             \
    f16x8 af[8];                                                                 \
    _Pragma("unroll")                                                            \
    for (int mi = 0; mi < 8; mi++) af[mi] = frag_ld(Ab, arow + mi * 16 + rr, kq);\
    f16x8 b0 = frag_ld(Bb, brow + rr, kq);                                       \
    f16x8 b1 = frag_ld(Bb, brow + 16 + rr, kq);                                  \
    if (STAGE) {                                                                 \
      const int qs = (KSRC) & 3;                                                 \
      async16(adst0 + qs * 16384, gA0 + (size_t)(KSRC) * 32);                    \
      async16(adst1 + qs * 16384, gA1 + (size_t)(KSRC) * 32);                    \
    }                                                                            \
    BAR();                                                                       \
    __builtin_amdgcn_s_setprio(1);                                               \
    _Pragma("unroll")                                                            \
    for (int mi = 0; mi < 8; mi++)                                               \
      acc[mi][0] = __builtin_amdgcn_mfma_f32_16x16x32_f16(af[mi], b0, acc[mi][0], 0, 0, 0); \
    _Pragma("unroll")                                                            \
    for (int mi = 0; mi < 8; mi++)                                               \
      acc[mi][1] = __builtin_amdgcn_mfma_f32_16x16x32_f16(af[mi], b1, acc[mi][1], 0, 0, 0); \
    __builtin_amdgcn_s_setprio(0);                                               \
    BAR();                                                                       \
    f16x8 b2 = frag_ld(Bb, brow + 32 + rr, kq);                                  \
    f16x8 b3 = frag_ld(Bb, brow + 48 + rr, kq);                                  \
    if (STAGE) {                                                                 \
      const int qs = (KSRC) & 3;                                                 \
      async16(bdst0 + qs * 16384, gB0 + (size_t)(KSRC) * 32);                    \
      async16(bdst1 + qs * 16384, gB1 + (size_t)(KSRC) * 32);                    \
    }                                                                            \
    BAR();                                                                       \
    __builtin_amdgcn_s_setprio(1);                                               \
    _Pragma("unroll")                                                            \
    for (int mi = 0; mi < 8; mi++)                                               \
      acc[mi][2] = __builtin_amdgcn_mfma_f32_16x16x32_f16(af[mi], b2, acc[mi][2], 0, 0, 0); \
    _Pragma("unroll")                                                            \
    for (int mi = 0; mi < 8; mi++)                                               \
      acc[mi][3] = __builtin_amdgcn_mfma_f32_16x16x32_f16(af[mi], b3, acc[mi][3], 0, 0, 0); \
    __builtin_amdgcn_s_setprio(0);                                               \
    WAITSTMT;                                                                    \
    BAR();                                                                       \
  } while (0)

    int ti = 0;
    for (; ti < NT - 3; ++ti)
        TILE_STEP(ti & 3, 1, ti + 3, VMWAIT(8));
    TILE_STEP(ti & 3, 0, 0, VMWAIT(4)); ++ti;
    TILE_STEP(ti & 3, 0, 0, VMWAIT(0)); ++ti;
    TILE_STEP(ti & 3, 0, 0, (void)0);
#undef TILE_STEP

    // fused BN-affine epilogue, nontemporal fp32 stores
    const float s = scalep[0];
    const int colb = n0 + wc * 64 + rr;
    const int rowb = m0 + wr * 128 + (kq << 2);
#pragma unroll
    for (int ni = 0; ni < 4; ni++) {
        const int col = colb + ni * 16;
        const float rv    = rsqrtf(var[col] + 1e-5f);
        const float alpha = rv * bnw[col] * s;
        const float beta  = (bias[col] - mean[col]) * alpha + bnb[col] * s;
#pragma unroll
        for (int mi = 0; mi < 8; mi++)
#pragma unroll
            for (int i = 0; i < 4; i++)
                __builtin_nontemporal_store(acc[mi][ni][i] * alpha + beta,
                    &C[(size_t)(rowb + mi * 16 + i) * N + col]);
    }
}

// ---------------------------------------------------------------- converts

__global__ __launch_bounds__(256) void cvt_x_kernel(const float4* __restrict__ in,
                                                    f16x4* __restrict__ outp, long n4) {
    long i = (long)blockIdx.x * blockDim.x + threadIdx.x;
    const long stride = (long)gridDim.x * blockDim.x;
    for (; i < n4; i += stride) {
        float4 v = in[i];
        f16x4 h = { (_Float16)v.x, (_Float16)v.y, (_Float16)v.z, (_Float16)v.w };
        outp[i] = h;
    }
}

// w [K][N] fp32 -> wt [N][K] fp16
__global__ __launch_bounds__(256) void transpose_w_kernel(const float* __restrict__ w,
                                                          _Float16* __restrict__ wt,
                                                          int K, int N) {
    __shared__ _Float16 tile[32][33];
    const int n0 = blockIdx.x * 32;
    const int k0 = blockIdx.y * 32;
    for (int i = threadIdx.y; i < 32; i += 8)
        tile[i][threadIdx.x] = (_Float16)w[(size_t)(k0 + i) * N + n0 + threadIdx.x];
    __syncthreads();
    for (int i = threadIdx.y; i < 32; i += 8)
        wt[(size_t)(n0 + i) * K + k0 + threadIdx.x] = tile[threadIdx.x][i];
}

// ------------------------------------------------- fallback GEMM (no ws)

__device__ __forceinline__ void mfma_step_128(const _Float16* As, const _Float16* Bs,
                                              f32x4 (&acc)[4][4], int lane, int wr, int wc) {
    const int kk = (lane >> 4) * 8;
    const int rr = lane & 15;
    f16x8 af[4], bf[4];
#pragma unroll
    for (int mi = 0; mi < 4; mi++)
        af[mi] = *(const f16x8*)(As + (size_t)(wr * 64 + mi * 16 + rr) * 32 + kk);
#pragma unroll
    for (int ni = 0; ni < 4; ni++)
        bf[ni] = *(const f16x8*)(Bs + (size_t)(wc * 64 + ni * 16 + rr) * 32 + kk);
#pragma unroll
    for (int mi = 0; mi < 4; mi++)
#pragma unroll
        for (int ni = 0; ni < 4; ni++)
            acc[mi][ni] = __builtin_amdgcn_mfma_f32_16x16x32_f16(af[mi], bf[ni], acc[mi][ni], 0, 0, 0);
}

__global__ __launch_bounds__(256) void gemm_f32src_bn(const float* __restrict__ X,
                                                      const float* __restrict__ W,
                                                      float* __restrict__ C,
                                                      const float* __restrict__ bias,
                                                      const float* __restrict__ mean,
                                                      const float* __restrict__ var,
                                                      const float* __restrict__ bnw,
                                                      const float* __restrict__ bnb,
                                                      const float* __restrict__ scalep,
                                                      int M, int N, int K) {
    __shared__ _Float16 As[128 * 32];
    __shared__ _Float16 Bs[128 * 32];

    const int nwg = gridDim.x;
    const int cpx = nwg >> 3;
    int bid = blockIdx.x;
    int swz = ((nwg & 7) == 0) ? (bid & 7) * cpx + (bid >> 3) : bid;
    const int ntn = N / 128;
    const int m0 = (swz / ntn) * 128, n0 = (swz % ntn) * 128;

    const int t = threadIdx.x;
    const int lane = t & 63, w = t >> 6;
    const int wr = w >> 1, wc = w & 1;

    f32x4 acc[4][4] = {};

    for (int k0 = 0; k0 < K; k0 += 32) {
        __syncthreads();
#pragma unroll
        for (int p = 0; p < 4; p++) {
            const int r = p * 32 + (t >> 3);
            const int c = (t & 7) * 4;
            float4 v = *(const float4*)&X[(size_t)(m0 + r) * K + k0 + c];
            f16x4 h = { (_Float16)v.x, (_Float16)v.y, (_Float16)v.z, (_Float16)v.w };
            *(f16x4*)&As[(size_t)r * 32 + c] = h;
        }
#pragma unroll
        for (int p = 0; p < 4; p++) {
            const int kk = p * 8 + (t >> 5);
            const int nn = (t & 31) * 4;
            float4 v = *(const float4*)&W[(size_t)(k0 + kk) * N + n0 + nn];
            Bs[(size_t)(nn + 0) * 32 + kk] = (_Float16)v.x;
            Bs[(size_t)(nn + 1) * 32 + kk] = (_Float16)v.y;
            Bs[(size_t)(nn + 2) * 32 + kk] = (_Float16)v.z;
            Bs[(size_t)(nn + 3) * 32 + kk] = (_Float16)v.w;
        }
        __syncthreads();
        mfma_step_128(As, Bs, acc, lane, wr, wc);
    }

    const float s = scalep[0];
    const int colbase = n0 + wc * 64 + (lane & 15);
    const int rowbase = m0 + wr * 64 + ((lane >> 4) << 2);
#pragma unroll
    for (int ni = 0; ni < 4; ni++) {
        const int col = colbase + ni * 16;
        const float r     = rsqrtf(var[col] + 1e-5f);
        const float alpha = r * bnw[col] * s;
        const float beta  = (bias[col] - mean[col]) * alpha + bnb[col] * s;
#pragma unroll
        for (int mi = 0; mi < 4; mi++)
#pragma unroll
            for (int i = 0; i < 4; i++)
                C[(size_t)(rowbase + mi * 16 + i) * N + col] = acc[mi][ni][i] * alpha + beta;
    }
}

// ---------------------------------------------------------------- softmax

__global__ __launch_bounds__(256) void softmax_rows(float* __restrict__ out, int N) {
    __shared__ float red[8];
    float4* p = (float4*)(out + (size_t)blockIdx.x * N);
    const int t = threadIdx.x;
    const int lane = t & 63, wid = t >> 6;

    float4 v[4];
    float mx = -3.4e38f;
#pragma unroll
    for (int i = 0; i < 4; i++) {
        v[i] = p[t + 256 * i];
        mx = fmaxf(mx, fmaxf(fmaxf(v[i].x, v[i].y), fmaxf(v[i].z, v[i].w)));
    }
#pragma unroll
    for (int off = 32; off >= 1; off >>= 1) mx = fmaxf(mx, __shfl_xor(mx, off));
    if (lane == 0) red[wid] = mx;
    __syncthreads();
    mx = fmaxf(fmaxf(red[0], red[1]), fmaxf(red[2], red[3]));

    float sum = 0.f;
#pragma unroll
    for (int i = 0; i < 4; i++) {
        v[i].x = __expf(v[i].x - mx); v[i].y = __expf(v[i].y - mx);
        v[i].z = __expf(v[i].z - mx); v[i].w = __expf(v[i].w - mx);
        sum += v[i].x + v[i].y + v[i].z + v[i].w;
    }
#pragma unroll
    for (int off = 32; off >= 1; off >>= 1) sum += __shfl_xor(sum, off);
    if (lane == 0) red[4 + wid] = sum;
    __syncthreads();
    sum = red[4] + red[5] + red[6] + red[7];

    const float inv = 1.0f / sum;
#pragma unroll
    for (int i = 0; i < 4; i++) {
        v[i].x *= inv; v[i].y *= inv; v[i].z *= inv; v[i].w *= inv;
        p[t + 256 * i] = v[i];
    }
}

// ---------------------------------------------------------------- launch

extern "C" void kernel_launch(void* const* d_in, const int* in_sizes, int n_in,
                              void* d_out, int out_size, void* d_ws, size_t ws_size,
                              hipStream_t stream) {
    const float* x     = (const float*)d_in[0];
    const float* w     = (const float*)d_in[1];
    const float* bias  = (const float*)d_in[2];
    const float* mean  = (const float*)d_in[3];
    const float* var   = (const float*)d_in[4];
    const float* bnw   = (const float*)d_in[5];
    const float* bnb   = (const float*)d_in[6];
    const float* scale = (const float*)d_in[7];
    float* out = (float*)d_out;

    const int N = in_sizes[2];
    const int K = in_sizes[1] / N;
    const int M = in_sizes[0] / K;

    const size_t xh_bytes = (size_t)M * K * sizeof(_Float16);
    const size_t wh_bytes = (size_t)N * K * sizeof(_Float16);

    if (ws_size >= xh_bytes + wh_bytes && (M & 255) == 0 && (N & 255) == 0 && (K >> 5) >= 4) {
        _Float16* x16 = (_Float16*)d_ws;
        _Float16* wt16 = (_Float16*)((char*)d_ws + xh_bytes);
        cvt_x_kernel<<<2048, 256, 0, stream>>>((const float4*)x, (f16x4*)x16,
                                               (long)M * K / 4);
        transpose_w_kernel<<<dim3(N / 32, K / 32), dim3(32, 8), 0, stream>>>(w, wt16, K, N);
        const int nblocks = (M >> 8) * (N >> 8);
        gemm_f16_bn_8p<<<nblocks, 512, 0, stream>>>(x16, wt16, out, bias, mean, var,
                                                    bnw, bnb, scale, M, N, K);
    } else {
        const int nblocks = (M / 128) * (N / 128);
        gemm_f32src_bn<<<nblocks, 256, 0, stream>>>(x, w, out, bias, mean, var,
                                                    bnw, bnb, scale, M, N, K);
    }
    softmax_rows<<<M, 256, 0, stream>>>(out, N);
}